// Round 8
// baseline (191.606 us; speedup 1.0000x reference)
//
#include <hip/hip_runtime.h>
#include <hip/hip_bf16.h>

#define NN 50000
#define EE 800000
#define FF 144
#define CVTBLK 1758      // ceil(NN*FF/16/256)
#define ECHK 2048        // edges per partition block (391 blocks: occupancy > write locality)
#define NBE 391          // ceil(EE/ECHK)
#define NBKT_REAL 391    // row buckets of 128 rows (covers 50048)
#define NBUCKET 392      // + 1 self-loop bucket
#define WGRID 284        // ceil(3*144*168/256)
#define HM (NBUCKET * NBE)   // 153272 histogram entries
#define SCANBLK 599      // ceil(HM/256)

typedef __hip_bfloat16 bf16;
typedef __attribute__((ext_vector_type(8))) short short8;
typedef __attribute__((ext_vector_type(4))) float floatx4;
typedef __attribute__((ext_vector_type(2))) float float2v;

__device__ inline float blo(unsigned x) { return __uint_as_float(x << 16); }
__device__ inline float bhi(unsigned x) { return __uint_as_float(x & 0xffff0000u); }

// ---- fp8 e4m3 pack/unpack (gfx950 OCP) ----
__device__ inline void dec4fma(float* a, float l, unsigned d) {
    float2v p0 = __builtin_amdgcn_cvt_pk_f32_fp8((int)d, false);
    float2v p1 = __builtin_amdgcn_cvt_pk_f32_fp8((int)d, true);
    a[0] = fmaf(l, p0.x, a[0]);
    a[1] = fmaf(l, p0.y, a[1]);
    a[2] = fmaf(l, p1.x, a[2]);
    a[3] = fmaf(l, p1.y, a[3]);
}
__device__ inline void fma16q(float* a, float l, uint4 u) {
    dec4fma(a + 0, l, u.x);
    dec4fma(a + 4, l, u.y);
    dec4fma(a + 8, l, u.z);
    dec4fma(a + 12, l, u.w);
}
__device__ inline unsigned enc4(float a, float b, float c, float d) {
    int w = __builtin_amdgcn_cvt_pk_fp8_f32(a, b, 0, false);
    w = __builtin_amdgcn_cvt_pk_fp8_f32(c, d, w, true);
    return (unsigned)w;
}

__device__ inline void load_edge(const int* ei, int e, int flag, int& r, int& c) {
    if (flag) { r = ei[2 * e]; c = ei[2 * EE + 2 * e]; }
    else      { r = ei[e];     c = ei[EE + e]; }
}

// ---------------- fused A: cvt(x) | detect+pack+bucket-hist(edges) | cvt+fold(W) ----------------

__global__ void fusedA_k(const float* __restrict__ x, bf16* __restrict__ xb,
                         unsigned char* __restrict__ xq,
                         const int* __restrict__ ei, const float* __restrict__ ew,
                         unsigned long long* __restrict__ items, int* __restrict__ hist,
                         const float* __restrict__ wt, short* __restrict__ wtb) {
    __shared__ int lh[NBUCKET];
    __shared__ int nzf;
    int b = blockIdx.x;
    int tid = threadIdx.x;
    if (b < CVTBLK) {
        int t = b * 256 + tid;
        if (t >= NN * FF / 16) return;
        const float4* xp = (const float4*)x + t * 4;
        float4 v0 = xp[0], v1 = xp[1], v2 = xp[2], v3 = xp[3];
        float f[16] = {v0.x, v0.y, v0.z, v0.w, v1.x, v1.y, v1.z, v1.w,
                       v2.x, v2.y, v2.z, v2.w, v3.x, v3.y, v3.z, v3.w};
        unsigned short hs[16];
        #pragma unroll
        for (int j = 0; j < 16; ++j) {
            bf16 bb = (bf16)f[j];
            hs[j] = *(unsigned short*)&bb;
        }
        uint4* xbq = (uint4*)xb + t * 2;
        xbq[0] = ((uint4*)hs)[0];
        xbq[1] = ((uint4*)hs)[1];
        uint4 q;
        q.x = enc4(f[0], f[1], f[2], f[3]);
        q.y = enc4(f[4], f[5], f[6], f[7]);
        q.z = enc4(f[8], f[9], f[10], f[11]);
        q.w = enc4(f[12], f[13], f[14], f[15]);
        ((uint4*)xq)[t] = q;
    } else if (b < CVTBLK + NBE) {
        int bb = b - CVTBLK;
        if (tid == 0) nzf = 0;
        for (int j = tid; j < NBUCKET; j += 256) lh[j] = 0;
        __syncthreads();
        int eb = bb * ECHK;
        unsigned acc = 0;
        #pragma unroll
        for (int k = 0; k < ECHK / 256; ++k) {
            int e = eb + k * 256 + tid;
            if (e < EE) acc |= (unsigned)ei[2 * e + 1];
        }
        if (acc) nzf = 1;   // benign race, resolved by barrier
        __syncthreads();
        int flag = (nzf == 0) ? 1 : 0;
        #pragma unroll
        for (int k = 0; k < ECHK / 256; ++k) {
            int e = eb + k * 256 + tid;
            if (e < EE) {
                int r, c; load_edge(ei, e, flag, r, c);
                unsigned key = (r == c) ? 0xFFFFu : (unsigned)r;
                items[e] = ((unsigned long long)((key << 16) | (unsigned)c) << 32)
                           | (unsigned long long)__float_as_uint(ew[e]);
                atomicAdd(&lh[min(key >> 7, (unsigned)NBKT_REAL)], 1);  // LDS
            }
        }
        __syncthreads();
        for (int j = tid; j < NBUCKET; j += 256) hist[j * NBE + bb] = lh[j];
    } else {
        int t = (b - CVTBLK - NBE) * 256 + tid;
        if (t >= 3 * FF * 168) return;
        int ph = t / (FF * 168);
        int rem = t - ph * FF * 168;
        int o = rem / 168;
        int i = rem - o * 168;
        short v = 0;
        if (i < FF) {
            // weight folding: out = x@(W0-W2) + T1@W1 + (L@T1)@(2*W2)
            float fv;
            if (ph == 0)      fv = wt[i * FF + o] - wt[2 * FF * FF + i * FF + o];
            else if (ph == 1) fv = wt[FF * FF + i * FF + o];
            else              fv = 2.0f * wt[2 * FF * FF + i * FF + o];
            bf16 bv = (bf16)fv;
            v = *(const short*)&bv;
        }
        wtb[t] = v;
    }
}

// ---------------- generic 2-level exclusive scan of hist[HM] (in place) ----------------

__global__ void scanA1_k(int* __restrict__ hist, int* __restrict__ bsumA) {
    __shared__ int wsum[4], woff[4];
    int b = blockIdx.x, tid = threadIdx.x;
    int wv = tid >> 6, ln = tid & 63;
    int i = b * 256 + tid;
    int v = (i < HM) ? hist[i] : 0;
    int xs = v;
    #pragma unroll
    for (int off = 1; off < 64; off <<= 1) {
        int t = __shfl_up(xs, off, 64);
        if (ln >= off) xs += t;
    }
    if (ln == 63) wsum[wv] = xs;
    __syncthreads();
    if (tid == 0) {
        int s = 0;
        #pragma unroll
        for (int j = 0; j < 4; ++j) { woff[j] = s; s += wsum[j]; }
        bsumA[b] = s;
    }
    __syncthreads();
    if (i < HM) hist[i] = woff[wv] + (xs - v);
}

__global__ __launch_bounds__(1024) void scanA2_k(int* __restrict__ bsumA) {
    __shared__ int wsum[16], woff[16];
    int tid = threadIdx.x, wv = tid >> 6, ln = tid & 63;
    int v = (tid < SCANBLK) ? bsumA[tid] : 0;
    int xs = v;
    #pragma unroll
    for (int off = 1; off < 64; off <<= 1) {
        int t = __shfl_up(xs, off, 64);
        if (ln >= off) xs += t;
    }
    if (ln == 63) wsum[wv] = xs;
    __syncthreads();
    if (tid == 0) {
        int s = 0;
        #pragma unroll
        for (int j = 0; j < 16; ++j) { woff[j] = s; s += wsum[j]; }
    }
    __syncthreads();
    if (tid < SCANBLK) bsumA[tid] = woff[wv] + (xs - v);
}

__device__ inline int hbase(const int* hist, const int* bsumA, int f) {
    return hist[f] + bsumA[f >> 8];
}

// ---------------- partition scatter: items -> sorted (grouped by bucket) ----------------

__global__ void pscat_k(const unsigned long long* __restrict__ items,
                        const int* __restrict__ hist, const int* __restrict__ bsumA,
                        unsigned long long* __restrict__ sorted) {
    __shared__ int lbase[NBUCKET];
    int b = blockIdx.x, tid = threadIdx.x;
    for (int j = tid; j < NBUCKET; j += 256) {
        int f = j * NBE + b;
        lbase[j] = hbase(hist, bsumA, f);
    }
    __syncthreads();
    int eb = b * ECHK;
    #pragma unroll
    for (int k = 0; k < ECHK / 256; ++k) {
        int e = eb + k * 256 + tid;
        if (e < EE) {
            unsigned long long it = items[e];
            unsigned key = (unsigned)(it >> 48);
            int bk = (int)min(key >> 7, (unsigned)NBKT_REAL);
            int slot = atomicAdd(&lbase[bk], 1);   // LDS
            sorted[slot] = it;
        }
    }
}

// ---------------- fine1: per-bucket row histogram -> rowptr + dinv ----------------

__global__ void fine1_k(const unsigned long long* __restrict__ sorted,
                        const int* __restrict__ hist, const int* __restrict__ bsumA,
                        int* __restrict__ rowptr, float* __restrict__ dinv) {
    __shared__ int lh[128];
    __shared__ int wtot;
    int b = blockIdx.x, tid = threadIdx.x;
    if (tid < 128) lh[tid] = 0;
    int s = hbase(hist, bsumA, b * NBE);
    int e = hbase(hist, bsumA, (b + 1) * NBE);
    __syncthreads();
    for (int p = s + tid; p < e; p += 256)
        atomicAdd(&lh[(int)(unsigned)(sorted[p] >> 48) - b * 128], 1);  // LDS
    __syncthreads();
    int ln = tid & 63;
    int v = (tid < 128) ? lh[tid] : 0;
    int xs = v;
    #pragma unroll
    for (int off = 1; off < 64; off <<= 1) {
        int t = __shfl_up(xs, off, 64);
        if (ln >= off) xs += t;
    }
    if (tid == 63) wtot = xs;
    __syncthreads();
    int excl = xs - v + ((tid >= 64 && tid < 128) ? wtot : 0);
    int gr = b * 128 + tid;
    if (tid < 128 && gr < NN) {
        rowptr[gr] = s + excl;
        dinv[gr] = v > 0 ? rsqrtf((float)v) : 0.f;
    }
    if (b == NBKT_REAL - 1 && tid == 0) rowptr[NN] = e;  // end of real edges
}

// ---------------- fine2: write pairs in CSR order (coalesced region per bucket) ----------------

__global__ void fine2_k(const unsigned long long* __restrict__ sorted,
                        const int* __restrict__ hist, const int* __restrict__ bsumA,
                        const int* __restrict__ rowptr, const float* __restrict__ dinv,
                        unsigned* __restrict__ pairs) {
    __shared__ int lrp[128];
    __shared__ float ldv[128];
    int b = blockIdx.x, tid = threadIdx.x;
    int gr = b * 128 + tid;
    if (tid < 128) {
        lrp[tid] = (gr < NN) ? rowptr[gr] : 0;
        ldv[tid] = (gr < NN) ? dinv[gr] : 0.f;
    }
    int s = hbase(hist, bsumA, b * NBE);
    int e = hbase(hist, bsumA, (b + 1) * NBE);
    __syncthreads();
    for (int p = s + tid; p < e; p += 256) {
        unsigned long long it = sorted[p];
        int lr = (int)(unsigned)(it >> 48) - b * 128;
        unsigned c = (unsigned)(it >> 32) & 0xFFFFu;
        float w = __uint_as_float((unsigned)it);
        float lap = -ldv[lr] * dinv[c] * w;
        int slot = atomicAdd(&lrp[lr], 1);   // LDS
        bf16 lb = (bf16)lap;
        pairs[slot] = c | ((unsigned)*(unsigned short*)&lb << 16);
    }
}

// ---------------- SpMM fp8-gather: 9 threads/node, 16 fp8/edge ----------------
// Unroll x4: 4 gather lines in flight per thread (latency/MLP-bound loop).
// Same accumulation order as unroll-2 (sequential p) -> bit-identical.

template <int WRITEQ>
__global__ void spmm_k(const unsigned char* __restrict__ vq,
                       const int* __restrict__ rowptr, const unsigned* __restrict__ pairs,
                       bf16* __restrict__ y, unsigned char* __restrict__ yq) {
    int t = blockIdx.x * 256 + threadIdx.x;
    if (t >= NN * 9) return;
    int i = t / 9;
    int fo = (t - i * 9) * 16;
    const unsigned char* vp = vq + fo;

    float a[16];
    #pragma unroll
    for (int j = 0; j < 16; ++j) a[j] = 0.f;

    int s = rowptr[i], e = rowptr[i + 1];
    int p = s;
    for (; p + 3 < e; p += 4) {
        unsigned pr0 = pairs[p], pr1 = pairs[p + 1];
        unsigned pr2 = pairs[p + 2], pr3 = pairs[p + 3];
        uint4 u0 = *(const uint4*)(vp + (pr0 & 0xffffu) * FF);
        uint4 u1 = *(const uint4*)(vp + (pr1 & 0xffffu) * FF);
        uint4 u2 = *(const uint4*)(vp + (pr2 & 0xffffu) * FF);
        uint4 u3 = *(const uint4*)(vp + (pr3 & 0xffffu) * FF);
        fma16q(a, bhi(pr0), u0);
        fma16q(a, bhi(pr1), u1);
        fma16q(a, bhi(pr2), u2);
        fma16q(a, bhi(pr3), u3);
    }
    for (; p < e; ++p) {
        unsigned pr = pairs[p];
        uint4 u = *(const uint4*)(vp + (pr & 0xffffu) * FF);
        fma16q(a, bhi(pr), u);
    }

    unsigned short hs[16];
    #pragma unroll
    for (int j = 0; j < 16; ++j) {
        bf16 b = (bf16)a[j];
        hs[j] = *(unsigned short*)&b;
    }
    uint4* yp = (uint4*)((unsigned short*)y + i * FF + fo);
    yp[0] = ((uint4*)hs)[0];
    yp[1] = ((uint4*)hs)[1];

    if (WRITEQ) {
        uint4 q;
        q.x = enc4(a[0], a[1], a[2], a[3]);
        q.y = enc4(a[4], a[5], a[6], a[7]);
        q.z = enc4(a[8], a[9], a[10], a[11]);
        q.w = enc4(a[12], a[13], a[14], a[15]);
        *(uint4*)(yq + i * FF + fo) = q;
    }
}

// ---------------- fused MFMA GEMM: full W in LDS, 1 block/CU, 16 waves ----------------
// Rolling A-prefetch: phase ph+1's 5 short8 loads issue BEFORE phase ph's 45 MFMAs,
// hiding the HBM latency under compute. VGPR ~100 <= 128 (16-wave residency kept).

__global__ __launch_bounds__(1024)
void gemm_fused(const bf16* __restrict__ A0, const bf16* __restrict__ A1,
                const bf16* __restrict__ A2, const short* __restrict__ wtb,
                const float* __restrict__ bias, float* __restrict__ out) {
    __shared__ __align__(16) short Wt[3 * 144 * 168];   // 145,152 B
    int tid = threadIdx.x;

    {
        const uint4* Wg = (const uint4*)wtb;
        uint4* Wl = (uint4*)Wt;
        #pragma unroll
        for (int q = 0; q < 9; ++q) {
            int idx = q * 1024 + tid;
            if (idx < 9072) Wl[idx] = Wg[idx];
        }
    }
    __syncthreads();   // the ONLY barrier

    int wv = tid >> 6, ln = tid & 63;
    int m16 = ln & 15, quad = ln >> 4;
    int tile = wv * 256 + blockIdx.x;
    if (tile * 16 >= NN) return;
    int rowBase = tile * 16;
    int row = rowBase + m16;

    const bf16* const srcs[3] = {A0, A1, A2};
    const short8 zero8 = {0, 0, 0, 0, 0, 0, 0, 0};

    floatx4 acc[9];
    #pragma unroll
    for (int q = 0; q < 9; ++q) acc[q] = (floatx4){0.f, 0.f, 0.f, 0.f};

    short8 a_cur[5], a_nxt[5];
    #pragma unroll
    for (int kt = 0; kt < 5; ++kt) {
        int k0 = kt * 32 + quad * 8;
        a_cur[kt] = (k0 < FF) ? *(const short8*)((const short*)A0 + row * FF + k0) : zero8;
    }

    #pragma unroll
    for (int ph = 0; ph < 3; ++ph) {
        if (ph < 2) {
            const bf16* An = srcs[ph + 1];
            #pragma unroll
            for (int kt = 0; kt < 5; ++kt) {
                int k0 = kt * 32 + quad * 8;
                a_nxt[kt] = (k0 < FF) ? *(const short8*)((const short*)An + row * FF + k0) : zero8;
            }
        }

        const short* Wp = Wt + ph * 144 * 168;
        #pragma unroll
        for (int nt = 0; nt < 9; ++nt) {
            #pragma unroll
            for (int kt = 0; kt < 5; ++kt) {
                short8 b = *(const short8*)&Wp[(nt * 16 + m16) * 168 + kt * 32 + quad * 8];
                acc[nt] = __builtin_amdgcn_mfma_f32_16x16x32_bf16(a_cur[kt], b, acc[nt], 0, 0, 0);
            }
        }

        if (ph < 2) {
            #pragma unroll
            for (int kt = 0; kt < 5; ++kt) a_cur[kt] = a_nxt[kt];
        }
    }

    int rowc = rowBase + quad * 4;
    #pragma unroll
    for (int nt = 0; nt < 9; ++nt) {
        int col = nt * 16 + m16;
        float bs = bias[col];
        #pragma unroll
        for (int r = 0; r < 4; ++r) {
            int rr = rowc + r;
            out[rr * FF + col] = acc[nt][r] + bs;
        }
    }
}

// ---------------- launch ----------------

extern "C" void kernel_launch(void* const* d_in, const int* in_sizes, int n_in,
                              void* d_out, int out_size, void* d_ws, size_t ws_size,
                              hipStream_t stream) {
    int ix = -1, iei = -1, iew = -1, iwt = -1, ib = -1;
    for (int i = 0; i < n_in; ++i) {
        switch (in_sizes[i]) {
            case NN * FF:      if (ix  < 0) ix  = i; break;
            case 2 * EE:       if (iei < 0) iei = i; break;
            case EE:           if (iew < 0) iew = i; break;
            case 3 * FF * FF:  if (iwt < 0) iwt = i; break;
            case FF:           if (ib  < 0) ib  = i; break;
        }
    }
    if (ix < 0 || iei < 0 || iew < 0 || iwt < 0 || ib < 0) {
        ix = 0; iei = 1; iew = 2; iwt = 3; ib = 4;
    }
    const float* x    = (const float*)d_in[ix];
    const int*   ei   = (const int*)d_in[iei];
    const float* ew   = (const float*)d_in[iew];
    const float* wt   = (const float*)d_in[iwt];
    const float* bias = (const float*)d_in[ib];
    float* out = (float*)d_out;

    char* p = (char*)d_ws;
    unsigned long long* items  = (unsigned long long*)(p + 0);          // 6.4 MB
    unsigned long long* sorted = (unsigned long long*)(p + 6400000);    // 6.4 MB
    int*      hist   = (int*)(p + 12800000);             // HM ints = 613 KB
    int*      bsumA  = (int*)(p + 13500000);             // SCANBLK ints
    int*      rowptr = (int*)(p + 13600000);             // N+1 ints
    float*    dinv   = (float*)(p + 13900000);           // N floats
    unsigned* pairs  = (unsigned*)(p + 14200000);        // E words = 3.2 MB
    short*    wtb    = (short*)(p + 17500000);           // 145,152 B
    bf16*     tx1    = (bf16*)(p + 17700000);            // 14.4 MB
    bf16*     tx2    = (bf16*)(p + 32100000);            // 14.4 MB
    unsigned char* xq   = (unsigned char*)(p + 46500000); // 7.2 MB
    unsigned char* tx1q = (unsigned char*)(p + 53700000); // 7.2 MB
    bf16*     xb     = (bf16*)(p + 60900000);            // 14.4 MB -> ends 75,300,000

    if (ws_size < 75300000) return;

    int spGrid = (NN * 9 + 255) / 256;

    fusedA_k<<<CVTBLK + NBE + WGRID, 256, 0, stream>>>(x, xb, xq, ei, ew, items, hist,
                                                       wt, wtb);
    scanA1_k<<<SCANBLK, 256, 0, stream>>>(hist, bsumA);
    scanA2_k<<<1, 1024, 0, stream>>>(bsumA);
    pscat_k<<<NBE, 256, 0, stream>>>(items, hist, bsumA, sorted);
    fine1_k<<<NBKT_REAL, 256, 0, stream>>>(sorted, hist, bsumA, rowptr, dinv);
    fine2_k<<<NBKT_REAL, 256, 0, stream>>>(sorted, hist, bsumA, rowptr, dinv, pairs);

    spmm_k<1><<<spGrid, 256, 0, stream>>>(xq, rowptr, pairs, tx1, tx1q);
    spmm_k<0><<<spGrid, 256, 0, stream>>>(tx1q, rowptr, pairs, tx2, (unsigned char*)0);
    gemm_fused<<<256, 1024, 0, stream>>>(xb, tx1, tx2, wtb, bias, out);
}